// Round 3
// baseline (640.671 us; speedup 1.0000x reference)
//
#include <hip/hip_runtime.h>
#include <stdint.h>

#define TSEQ 1024
#define DDIM 512

typedef __attribute__((ext_vector_type(8))) short bf16x8;
typedef __attribute__((ext_vector_type(4))) float f32x4;

#define MFMA(a, b, c) __builtin_amdgcn_mfma_f32_16x16x32_bf16((a), (b), (c), 0, 0, 0)

__device__ __forceinline__ unsigned short f2bf(float f) {
  unsigned int u = __builtin_bit_cast(unsigned int, f);
  u += 0x7FFFu + ((u >> 16) & 1u);
  return (unsigned short)(u >> 16);
}

__device__ __forceinline__ void async_load16(const void* g, void* l) {
  __builtin_amdgcn_global_load_lds(
      (const __attribute__((address_space(1))) unsigned int*)g,
      (__attribute__((address_space(3))) unsigned int*)l, 16, 0, 0);
}

// ---------------- LayerNorm: x[65536][512] f32 -> nx bf16 ----------------
__global__ __launch_bounds__(256) void k_ln(const float* __restrict__ x,
                                            const float* __restrict__ gamma,
                                            const float* __restrict__ beta,
                                            unsigned short* __restrict__ nx) {
  const int wid = threadIdx.x >> 6, lane = threadIdx.x & 63;
  const long long row = (long long)blockIdx.x * 4 + wid;
  const float* xr = x + row * DDIM + lane * 8;
  float4 a = *(const float4*)xr;
  float4 b = *(const float4*)(xr + 4);
  float s = a.x + a.y + a.z + a.w + b.x + b.y + b.z + b.w;
  float s2 = a.x * a.x + a.y * a.y + a.z * a.z + a.w * a.w +
             b.x * b.x + b.y * b.y + b.z * b.z + b.w * b.w;
#pragma unroll
  for (int m = 1; m < 64; m <<= 1) {
    s += __shfl_xor(s, m);
    s2 += __shfl_xor(s2, m);
  }
  const float mu = s * (1.0f / DDIM);
  const float var = s2 * (1.0f / DDIM) - mu * mu;
  const float rsd = rsqrtf(var + 1e-5f);
  const float4 g0 = *(const float4*)(gamma + lane * 8);
  const float4 g1 = *(const float4*)(gamma + lane * 8 + 4);
  const float4 b0 = *(const float4*)(beta + lane * 8);
  const float4 b1 = *(const float4*)(beta + lane * 8 + 4);
  float o0 = (a.x - mu) * rsd * g0.x + b0.x;
  float o1 = (a.y - mu) * rsd * g0.y + b0.y;
  float o2 = (a.z - mu) * rsd * g0.z + b0.z;
  float o3 = (a.w - mu) * rsd * g0.w + b0.w;
  float o4 = (b.x - mu) * rsd * g1.x + b1.x;
  float o5 = (b.y - mu) * rsd * g1.y + b1.y;
  float o6 = (b.z - mu) * rsd * g1.z + b1.z;
  float o7 = (b.w - mu) * rsd * g1.w + b1.w;
  uint4 pk;
  pk.x = f2bf(o0) | ((unsigned)f2bf(o1) << 16);
  pk.y = f2bf(o2) | ((unsigned)f2bf(o3) << 16);
  pk.z = f2bf(o4) | ((unsigned)f2bf(o5) << 16);
  pk.w = f2bf(o6) | ((unsigned)f2bf(o7) << 16);
  *(uint4*)(nx + row * DDIM + lane * 8) = pk;
}

// ---------------- cast Wg f32 -> bf16 ----------------
__global__ __launch_bounds__(256) void k_cast(const float* __restrict__ w,
                                              unsigned short* __restrict__ o, int n8) {
  const int i = blockIdx.x * 256 + threadIdx.x;
  if (i >= n8) return;
  const float4 a = *(const float4*)(w + (size_t)i * 8);
  const float4 b = *(const float4*)(w + (size_t)i * 8 + 4);
  uint4 pk;
  pk.x = f2bf(a.x) | ((unsigned)f2bf(a.y) << 16);
  pk.y = f2bf(a.z) | ((unsigned)f2bf(a.w) << 16);
  pk.z = f2bf(b.x) | ((unsigned)f2bf(b.y) << 16);
  pk.w = f2bf(b.z) | ((unsigned)f2bf(b.w) << 16);
  *(uint4*)(o + (size_t)i * 8) = pk;
}

// ---------------- GEMM: qkv[M][512] = nx[M][512] @ Wg[512][512]^T ----------
// m97 structure: 128x128 tile, BK=64, 4 waves (2x2), LINEAR LDS (no swizzle),
// global_load_lds width=16, ds_read_b128 fragments.  (unchanged from R1)
__global__ __launch_bounds__(256, 2) void k_gemm(const unsigned short* __restrict__ A,
                                                 const unsigned short* __restrict__ B,
                                                 unsigned short* __restrict__ C) {
  __shared__ char As[16384];
  __shared__ char Bs[16384];
  const int tid = threadIdx.x;
  const int wid = tid >> 6, lane = tid & 63;
  const int g = lane >> 4, c = lane & 15;
  const int wr = wid >> 1, wc = wid & 1;
  const int bm = blockIdx.y, bn = blockIdx.x;

  int srcoff[4], ldsoff[4];
#pragma unroll
  for (int r = 0; r < 4; ++r) {
    const int aoff = r * 4096 + tid * 16;
    srcoff[r] = (aoff >> 7) * 1024 + (aoff & 127);
    ldsoff[r] = r * 4096 + (wid << 10);
  }
  const char* Ab = (const char*)A + (size_t)bm * 131072;
  const char* Bb = (const char*)B + (size_t)bn * 131072;

  f32x4 acc[4][4] = {};

  for (int ks = 0; ks < 8; ++ks) {
    __syncthreads();
#pragma unroll
    for (int r = 0; r < 4; ++r) {
      async_load16(Ab + ks * 128 + srcoff[r], As + ldsoff[r]);
      async_load16(Bb + ks * 128 + srcoff[r], Bs + ldsoff[r]);
    }
    __syncthreads();
    bf16x8 af[4][2], bfr[4][2];
#pragma unroll
    for (int f = 0; f < 4; ++f) {
#pragma unroll
      for (int kk = 0; kk < 2; ++kk) {
        const int rowa = wr * 64 + f * 16 + c;
        af[f][kk] = *(const bf16x8*)(As + rowa * 128 + (kk * 4 + g) * 16);
        const int rowb = wc * 64 + f * 16 + c;
        bfr[f][kk] = *(const bf16x8*)(Bs + rowb * 128 + (kk * 4 + g) * 16);
      }
    }
#pragma unroll
    for (int i = 0; i < 4; ++i) {
#pragma unroll
      for (int j = 0; j < 4; ++j) {
        acc[i][j] = MFMA(af[i][0], bfr[j][0], acc[i][j]);
        acc[i][j] = MFMA(af[i][1], bfr[j][1], acc[i][j]);
      }
    }
  }
#pragma unroll
  for (int i = 0; i < 4; ++i) {
#pragma unroll
    for (int r = 0; r < 4; ++r) {
      const long long row = (long long)bm * 128 + wr * 64 + i * 16 + g * 4 + r;
#pragma unroll
      for (int j = 0; j < 4; ++j) {
        const int col = bn * 128 + wc * 64 + j * 16 + c;
        C[row * DDIM + col] = f2bf(acc[i][j][r]);
      }
    }
  }
}

// ---------------- Flash attention (causal), Q=K=V=qkv, + residual add --------
// R2: conflict-fixed LDS. K tile [64][1024B] with 16B-granule XOR swizzle
// (granule ^= row&7) on BOTH staging source and reads (rule #21). V^T built
// per-tile by an in-LDS transpose pass into vts[512][128B] (same swizzle) ->
// PV uses conflict-free ds_read_b128 instead of 512 scalar strided reads.
// Staging of tile t+1 issued mid-tile so HBM latency hides under softmax+PV.
__global__ __launch_bounds__(512, 2) void k_attn(const unsigned short* __restrict__ qkv,
                                                 const float* __restrict__ x,
                                                 float* __restrict__ xo) {
  __shared__ char kvs[65536];              // K: [kv=64][512d], granule-swizzled
  __shared__ char vts[65536];              // Vt: [d=512][64kv], granule-swizzled
  __shared__ unsigned short plds[8 * 1152];  // per wave [16][72] padded
  const int tid = threadIdx.x;
  const int wid = tid >> 6, lane = tid & 63;
  const int g = lane >> 4, c = lane & 15;
  const int bc = blockIdx.x;
  const int qt = 7 - blockIdx.y;  // heavy q-tiles dispatch first
  const size_t bcbase = (size_t)bc * TSEQ * DDIM;
  const int qrow = qt * 128 + wid * 16 + c;

  // Q fragments: lane holds Q[q = c][d = ks*32 + g*8 + j]
  bf16x8 qf[16];
  const unsigned short* qp = qkv + bcbase + (size_t)qrow * DDIM + g * 8;
#pragma unroll
  for (int ks = 0; ks < 16; ++ks) qf[ks] = *(const bf16x8*)(qp + ks * 32);

  f32x4 oacc[32] = {};
  float mrun = -1e30f, lrun = 0.0f;
  const float scale = 0.044194173824159216f;  // 512^-0.5

  unsigned short* pbuf = plds + wid * 1152;
  const int nkv = 2 * qt + 2;

  // staging: LDS linear dest (wave covers row r*8+wid), source granule
  // pre-swizzled:  LDS[row][gr] <- K[row][gr ^ (row&7)], row&7 == wid
  int soff[8];
#pragma unroll
  for (int r = 0; r < 8; ++r)
    soff[r] = (r * 8 + wid) * 1024 + ((lane ^ wid) << 4);

  {  // prologue: stage tile 0
    const char* tb = (const char*)(qkv + bcbase);
#pragma unroll
    for (int r = 0; r < 8; ++r)
      async_load16(tb + soff[r], kvs + r * 8192 + (wid << 10));
  }

  for (int kvt = 0; kvt < nkv; ++kvt) {
    __syncthreads();  // kvs = tile kvt ready; all prior vts/kvs readers drained

    // ---- transpose K -> Vt (this wave owns d in [wid*64, wid*64+64))
#pragma unroll
    for (int r = 0; r < 8; ++r) {
      const int gr = wid * 8 + r;  // K granule (8 d-values) at kv = lane
      const bf16x8 t = *(const bf16x8*)(kvs + lane * 1024 + ((gr ^ (lane & 7)) << 4));
#pragma unroll
      for (int j = 0; j < 8; ++j) {
        const int d = gr * 8 + j;  // d&7 == j
        *(short*)(vts + d * 128 + (((lane >> 3) ^ j) << 4) + (lane & 7) * 2) = t[j];
      }
    }

    // ---- QK^T (swapped): st[ft] holds S^T[kv = ft*16 + g*4 + r][q = c]
    f32x4 st[4] = {};
#pragma unroll
    for (int ks = 0; ks < 16; ++ks) {
#pragma unroll
      for (int ft = 0; ft < 4; ++ft) {
        const int row = ft * 16 + c;  // row&7 == c&7
        const bf16x8 kf =
            *(const bf16x8*)(kvs + row * 1024 + (((ks * 4 + g) ^ (c & 7)) << 4));
        st[ft] = MFMA(kf, qf[ks], st[ft]);
      }
    }

    __syncthreads();  // kvs free for restage; vts complete for PV

    if (kvt + 1 < nkv) {  // stage next tile; latency hides under softmax+PV
      const char* tb = (const char*)(qkv + bcbase + (size_t)(kvt + 1) * 64 * DDIM);
#pragma unroll
      for (int r = 0; r < 8; ++r)
        async_load16(tb + soff[r], kvs + r * 8192 + (wid << 10));
    }

    // ---- online softmax (per lane: q = c, 16 kv values)
    float sv[16];
#pragma unroll
    for (int ft = 0; ft < 4; ++ft) {
#pragma unroll
      for (int r = 0; r < 4; ++r) {
        const float v = st[ft][r] * scale;
        const int kvg = kvt * 64 + ft * 16 + g * 4 + r;
        sv[ft * 4 + r] = (kvg > qrow) ? -1e30f : v;
      }
    }
    float mt = sv[0];
#pragma unroll
    for (int i = 1; i < 16; ++i) mt = fmaxf(mt, sv[i]);
    mt = fmaxf(mt, __shfl_xor(mt, 16));
    mt = fmaxf(mt, __shfl_xor(mt, 32));
    const float mnew = fmaxf(mrun, mt);
    const float corr = __expf(mrun - mnew);
    float psum = 0.0f;
    unsigned int pw[8];
#pragma unroll
    for (int i = 0; i < 8; ++i) {
      const float p0 = __expf(sv[2 * i] - mnew);
      const float p1 = __expf(sv[2 * i + 1] - mnew);
      psum += p0 + p1;
      pw[i] = (unsigned)f2bf(p0) | ((unsigned)f2bf(p1) << 16);
    }
    psum += __shfl_xor(psum, 16);
    psum += __shfl_xor(psum, 32);
    lrun = lrun * corr + psum;
    mrun = mnew;

    // write P to per-wave LDS: row q=c (stride 72), cols ft*16 + g*4 + {0..3}
#pragma unroll
    for (int ft = 0; ft < 4; ++ft) {
      uint2 pk;
      pk.x = pw[2 * ft];
      pk.y = pw[2 * ft + 1];
      *(uint2*)(pbuf + c * 72 + ft * 16 + g * 4) = pk;
    }
    asm volatile("" ::: "memory");
    const bf16x8 pa0 = *(const bf16x8*)(pbuf + c * 72 + g * 8);
    const bf16x8 pa1 = *(const bf16x8*)(pbuf + c * 72 + 32 + g * 8);

    // rescale O by corr (oacc rows are q = g*4 + r)
    float cr[4];
#pragma unroll
    for (int r = 0; r < 4; ++r) cr[r] = __shfl(corr, g * 4 + r);
#pragma unroll
    for (int dt = 0; dt < 32; ++dt) {
      oacc[dt][0] *= cr[0];
      oacc[dt][1] *= cr[1];
      oacc[dt][2] *= cr[2];
      oacc[dt][3] *= cr[3];
    }

    // ---- PV from Vt: B-frag = Vt[row = dt*16+c][kv granule g (+4)]
#pragma unroll
    for (int dt = 0; dt < 32; ++dt) {
      const int row = dt * 16 + c;  // row&7 == c&7
      const bf16x8 b0 = *(const bf16x8*)(vts + row * 128 + ((g ^ (c & 7)) << 4));
      const bf16x8 b1 = *(const bf16x8*)(vts + row * 128 + (((4 + g) ^ (c & 7)) << 4));
      oacc[dt] = MFMA(pa0, b0, oacc[dt]);
      oacc[dt] = MFMA(pa1, b1, oacc[dt]);
    }
  }

  // ---- epilogue: x + O/l
  const float rl = 1.0f / lrun;
  float rlr[4];
#pragma unroll
  for (int r = 0; r < 4; ++r) rlr[r] = __shfl(rl, g * 4 + r);
#pragma unroll
  for (int dt = 0; dt < 32; ++dt) {
#pragma unroll
    for (int r = 0; r < 4; ++r) {
      const size_t off =
          bcbase + (size_t)(qt * 128 + wid * 16 + g * 4 + r) * DDIM + dt * 16 + c;
      xo[off] = x[off] + oacc[dt][r] * rlr[r];
    }
  }
}

// ---------------- cell mixing + sin pulse (in-place on d_out) ----------------
__global__ __launch_bounds__(256) void k_mix(float* __restrict__ xo,
                                             const float* __restrict__ inh,
                                             const float* __restrict__ phz,
                                             const float* __restrict__ rsc) {
  __shared__ float sI[256];
  __shared__ float sP[16];
  const int tid = threadIdx.x;
  sI[tid] = inh[tid];
  if (tid < 16) sP[tid] = phz[tid];
  __syncthreads();
  const float rs = rsc[0];
  const int idx = blockIdx.x * 256 + tid;
  const int d4 = idx & 127;
  const int t = (idx >> 7) & 1023;
  const int b = idx >> 17;
  float4* base = (float4*)xo + ((size_t)b * 16 * TSEQ + t) * 128 + d4;
  float4 v[16];
#pragma unroll
  for (int cc = 0; cc < 16; ++cc) v[cc] = base[(size_t)cc * TSEQ * 128];
#pragma unroll
  for (int k = 0; k < 16; ++k) {
    float4 comp = make_float4(0.f, 0.f, 0.f, 0.f);
#pragma unroll
    for (int cc = 0; cc < 16; ++cc) {
      const float w = sI[cc * 16 + k];
      comp.x += v[cc].x * w;
      comp.y += v[cc].y * w;
      comp.z += v[cc].z * w;
      comp.w += v[cc].w * w;
    }
    const float ph = sP[k];
    float4 o;
    o.x = v[k].x + __sinf(comp.x + ph) * rs;
    o.y = v[k].y + __sinf(comp.y + ph) * rs;
    o.z = v[k].z + __sinf(comp.z + ph) * rs;
    o.w = v[k].w + __sinf(comp.w + ph) * rs;
    base[(size_t)k * TSEQ * 128] = o;
  }
}

extern "C" void kernel_launch(void* const* d_in, const int* in_sizes, int n_in,
                              void* d_out, int out_size, void* d_ws, size_t ws_size,
                              hipStream_t stream) {
  const float* x = (const float*)d_in[0];
  // d_in[1] = mask (causal, strict upper triangle) -- implemented analytically
  const float* gamma = (const float*)d_in[2];
  const float* beta = (const float*)d_in[3];
  const float* Wg = (const float*)d_in[4];
  const float* inh = (const float*)d_in[5];
  const float* phz = (const float*)d_in[6];
  const float* rsc = (const float*)d_in[7];
  float* out = (float*)d_out;

  // workspace: wgb (0.5 MiB) + qkv (64 MiB). nx lives in d_out (dead before
  // k_attn writes real output there).
  unsigned short* wgb = (unsigned short*)d_ws;
  unsigned short* qkv = wgb + (size_t)262144;
  unsigned short* nx = (unsigned short*)d_out;

  k_cast<<<128, 256, 0, stream>>>(Wg, wgb, 32768);
  k_ln<<<16384, 256, 0, stream>>>(x, gamma, beta, nx);
  k_gemm<<<dim3(4, 512), 256, 0, stream>>>(nx, wgb, qkv);
  k_attn<<<dim3(64, 8), 512, 0, stream>>>(qkv, x, out);
  k_mix<<<2048, 256, 0, stream>>>(out, inh, phz, rsc);
}

// Round 4
// 587.452 us; speedup vs baseline: 1.0906x; 1.0906x over previous
//
#include <hip/hip_runtime.h>
#include <stdint.h>

#define TSEQ 1024
#define DDIM 512

typedef __attribute__((ext_vector_type(8))) short bf16x8;
typedef __attribute__((ext_vector_type(4))) short bf16x4;
typedef __attribute__((ext_vector_type(4))) float f32x4;

#define MFMA(a, b, c) __builtin_amdgcn_mfma_f32_16x16x32_bf16((a), (b), (c), 0, 0, 0)

__device__ __forceinline__ unsigned short f2bf(float f) {
  unsigned int u = __builtin_bit_cast(unsigned int, f);
  u += 0x7FFFu + ((u >> 16) & 1u);
  return (unsigned short)(u >> 16);
}

__device__ __forceinline__ void async_load16(const void* g, void* l) {
  __builtin_amdgcn_global_load_lds(
      (const __attribute__((address_space(1))) unsigned int*)g,
      (__attribute__((address_space(3))) unsigned int*)l, 16, 0, 0);
}

// ---------------- LayerNorm: x[65536][512] f32 -> nx bf16 ----------------
__global__ __launch_bounds__(256) void k_ln(const float* __restrict__ x,
                                            const float* __restrict__ gamma,
                                            const float* __restrict__ beta,
                                            unsigned short* __restrict__ nx) {
  const int wid = threadIdx.x >> 6, lane = threadIdx.x & 63;
  const long long row = (long long)blockIdx.x * 4 + wid;
  const float* xr = x + row * DDIM + lane * 8;
  float4 a = *(const float4*)xr;
  float4 b = *(const float4*)(xr + 4);
  float s = a.x + a.y + a.z + a.w + b.x + b.y + b.z + b.w;
  float s2 = a.x * a.x + a.y * a.y + a.z * a.z + a.w * a.w +
             b.x * b.x + b.y * b.y + b.z * b.z + b.w * b.w;
#pragma unroll
  for (int m = 1; m < 64; m <<= 1) {
    s += __shfl_xor(s, m);
    s2 += __shfl_xor(s2, m);
  }
  const float mu = s * (1.0f / DDIM);
  const float var = s2 * (1.0f / DDIM) - mu * mu;
  const float rsd = rsqrtf(var + 1e-5f);
  const float4 g0 = *(const float4*)(gamma + lane * 8);
  const float4 g1 = *(const float4*)(gamma + lane * 8 + 4);
  const float4 b0 = *(const float4*)(beta + lane * 8);
  const float4 b1 = *(const float4*)(beta + lane * 8 + 4);
  float o0 = (a.x - mu) * rsd * g0.x + b0.x;
  float o1 = (a.y - mu) * rsd * g0.y + b0.y;
  float o2 = (a.z - mu) * rsd * g0.z + b0.z;
  float o3 = (a.w - mu) * rsd * g0.w + b0.w;
  float o4 = (b.x - mu) * rsd * g1.x + b1.x;
  float o5 = (b.y - mu) * rsd * g1.y + b1.y;
  float o6 = (b.z - mu) * rsd * g1.z + b1.z;
  float o7 = (b.w - mu) * rsd * g1.w + b1.w;
  uint4 pk;
  pk.x = f2bf(o0) | ((unsigned)f2bf(o1) << 16);
  pk.y = f2bf(o2) | ((unsigned)f2bf(o3) << 16);
  pk.z = f2bf(o4) | ((unsigned)f2bf(o5) << 16);
  pk.w = f2bf(o6) | ((unsigned)f2bf(o7) << 16);
  *(uint4*)(nx + row * DDIM + lane * 8) = pk;
}

// ---------------- cast Wg f32 -> bf16 ----------------
__global__ __launch_bounds__(256) void k_cast(const float* __restrict__ w,
                                              unsigned short* __restrict__ o, int n8) {
  const int i = blockIdx.x * 256 + threadIdx.x;
  if (i >= n8) return;
  const float4 a = *(const float4*)(w + (size_t)i * 8);
  const float4 b = *(const float4*)(w + (size_t)i * 8 + 4);
  uint4 pk;
  pk.x = f2bf(a.x) | ((unsigned)f2bf(a.y) << 16);
  pk.y = f2bf(a.z) | ((unsigned)f2bf(a.w) << 16);
  pk.z = f2bf(b.x) | ((unsigned)f2bf(b.y) << 16);
  pk.w = f2bf(b.z) | ((unsigned)f2bf(b.w) << 16);
  *(uint4*)(o + (size_t)i * 8) = pk;
}

// ---------------- GEMM: qkv[M][512] = nx[M][512] @ Wg[512][512]^T ----------
// m97 structure (unchanged, verified R1/R2).
__global__ __launch_bounds__(256, 2) void k_gemm(const unsigned short* __restrict__ A,
                                                 const unsigned short* __restrict__ B,
                                                 unsigned short* __restrict__ C) {
  __shared__ char As[16384];
  __shared__ char Bs[16384];
  const int tid = threadIdx.x;
  const int wid = tid >> 6, lane = tid & 63;
  const int g = lane >> 4, c = lane & 15;
  const int wr = wid >> 1, wc = wid & 1;
  const int bm = blockIdx.y, bn = blockIdx.x;

  int srcoff[4], ldsoff[4];
#pragma unroll
  for (int r = 0; r < 4; ++r) {
    const int aoff = r * 4096 + tid * 16;
    srcoff[r] = (aoff >> 7) * 1024 + (aoff & 127);
    ldsoff[r] = r * 4096 + (wid << 10);
  }
  const char* Ab = (const char*)A + (size_t)bm * 131072;
  const char* Bb = (const char*)B + (size_t)bn * 131072;

  f32x4 acc[4][4] = {};

  for (int ks = 0; ks < 8; ++ks) {
    __syncthreads();
#pragma unroll
    for (int r = 0; r < 4; ++r) {
      async_load16(Ab + ks * 128 + srcoff[r], As + ldsoff[r]);
      async_load16(Bb + ks * 128 + srcoff[r], Bs + ldsoff[r]);
    }
    __syncthreads();
    bf16x8 af[4][2], bfr[4][2];
#pragma unroll
    for (int f = 0; f < 4; ++f) {
#pragma unroll
      for (int kk = 0; kk < 2; ++kk) {
        const int rowa = wr * 64 + f * 16 + c;
        af[f][kk] = *(const bf16x8*)(As + rowa * 128 + (kk * 4 + g) * 16);
        const int rowb = wc * 64 + f * 16 + c;
        bfr[f][kk] = *(const bf16x8*)(Bs + rowb * 128 + (kk * 4 + g) * 16);
      }
    }
#pragma unroll
    for (int i = 0; i < 4; ++i) {
#pragma unroll
      for (int j = 0; j < 4; ++j) {
        acc[i][j] = MFMA(af[i][0], bfr[j][0], acc[i][j]);
        acc[i][j] = MFMA(af[i][1], bfr[j][1], acc[i][j]);
      }
    }
  }
#pragma unroll
  for (int i = 0; i < 4; ++i) {
#pragma unroll
    for (int r = 0; r < 4; ++r) {
      const long long row = (long long)bm * 128 + wr * 64 + i * 16 + g * 4 + r;
#pragma unroll
      for (int j = 0; j < 4; ++j) {
        const int col = bn * 128 + wc * 64 + j * 16 + c;
        C[row * DDIM + col] = f2bf(acc[i][j][r]);
      }
    }
  }
}

// ---------------- qkv [bc][t][d] -> qkvT [bc][d][t] (tiled transpose) -------
__global__ __launch_bounds__(256) void k_vt(const unsigned short* __restrict__ qkv,
                                            unsigned short* __restrict__ qkvT) {
  __shared__ unsigned short t[64][72];  // 64x64 tile, padded rows (16B-aligned)
  const int ti = blockIdx.x;  // 16 t-tiles
  const int di = blockIdx.y;  // 8 d-tiles
  const int bc = blockIdx.z;  // 64
  const int tid = threadIdx.x;
  const int r = tid >> 3, c8 = tid & 7;
  const unsigned short* src = qkv + ((size_t)bc * TSEQ + ti * 64) * DDIM + di * 64;
#pragma unroll
  for (int p = 0; p < 2; ++p) {
    const bf16x8 v = *(const bf16x8*)(src + (size_t)(r + p * 32) * DDIM + c8 * 8);
    *(bf16x8*)&t[r + p * 32][c8 * 8] = v;
  }
  __syncthreads();
  unsigned short* dst = qkvT + ((size_t)bc * DDIM + di * 64) * TSEQ + ti * 64;
#pragma unroll
  for (int p = 0; p < 2; ++p) {
    const int d = r + p * 32;
    bf16x8 v;
#pragma unroll
    for (int j = 0; j < 8; ++j) v[j] = t[c8 * 8 + j][d];
    *(bf16x8*)(dst + (size_t)d * TSEQ + c8 * 8) = v;
  }
}

// ---------------- Flash attention (causal), Q=K=V=qkv, + residual add --------
// 80KiB LDS (64K swizzled K + 16K P) -> 2 blocks/CU (16 waves).
// QK^T swapped, swizzled reads (R2-verified). P via per-wave b64-granule XOR
// buffer. PV: VG=1 -> V^T frags as coalesced GLOBAL b128 loads from qkvT
// (no LDS); VG=0 fallback -> scalar strided LDS reads from kvs.
template <int VG>
__global__ __launch_bounds__(512, 2) void k_attn(const unsigned short* __restrict__ qkv,
                                                 const unsigned short* __restrict__ qkvT,
                                                 const float* __restrict__ x,
                                                 float* __restrict__ xo) {
  __shared__ char lds[81920];
  char* kvs = lds;
  const int tid = threadIdx.x;
  const int wid = tid >> 6, lane = tid & 63;
  const int g = lane >> 4, c = lane & 15;
  unsigned short* pbuf = (unsigned short*)(lds + 65536) + wid * 1024;  // [16 q][16 gran x 4]
  const int bc = blockIdx.x;
  const int qt = 7 - blockIdx.y;  // heavy q-tiles dispatch first
  const size_t bcbase = (size_t)bc * TSEQ * DDIM;
  const int qrow = qt * 128 + wid * 16 + c;

  // Q fragments: lane holds Q[q = c][d = ks*32 + g*8 + j]
  bf16x8 qf[16];
  const unsigned short* qp = qkv + bcbase + (size_t)qrow * DDIM + g * 8;
#pragma unroll
  for (int ks = 0; ks < 16; ++ks) qf[ks] = *(const bf16x8*)(qp + ks * 32);

  f32x4 oacc[32] = {};
  float mrun = -1e30f, lrun = 0.0f;
  const float scale = 0.044194173824159216f;  // 512^-0.5

  const int nkv = 2 * qt + 2;

  // staging: LDS linear; source granule pre-swizzled (gr ^= row&7, row&7==wid)
  int soff[8];
#pragma unroll
  for (int r = 0; r < 8; ++r) soff[r] = (r * 8 + wid) * 1024 + ((lane ^ wid) << 4);

  {  // prologue: stage tile 0
    const char* tb = (const char*)(qkv + bcbase);
#pragma unroll
    for (int r = 0; r < 8; ++r) async_load16(tb + soff[r], kvs + r * 8192 + (wid << 10));
  }

  const char* vtb = (const char*)qkvT + ((size_t)bc << 20);

  for (int kvt = 0; kvt < nkv; ++kvt) {
    __syncthreads();  // tile kvt staged; prior readers drained

    // ---- QK^T (swapped): st[ft] holds S^T[kv = ft*16 + g*4 + r][q = c]
    f32x4 st[4] = {};
#pragma unroll
    for (int ks = 0; ks < 16; ++ks) {
#pragma unroll
      for (int ft = 0; ft < 4; ++ft) {
        const bf16x8 kf =
            *(const bf16x8*)(kvs + (ft * 16 + c) * 1024 + (((ks * 4 + g) ^ (c & 7)) << 4));
        st[ft] = MFMA(kf, qf[ks], st[ft]);
      }
    }

    if (VG) {            // PV reads global -> kvs free after QK
      __syncthreads();   // all QK reads of kvs done
      if (kvt + 1 < nkv) {  // stage next; latency hides under softmax+PV
        const char* tb = (const char*)(qkv + bcbase + (size_t)(kvt + 1) * 64 * DDIM);
#pragma unroll
        for (int r = 0; r < 8; ++r)
          async_load16(tb + soff[r], kvs + r * 8192 + (wid << 10));
      }
    }

    // ---- online softmax (per lane: q = c, 16 kv values)
    float sv[16];
#pragma unroll
    for (int ft = 0; ft < 4; ++ft) {
#pragma unroll
      for (int r = 0; r < 4; ++r) {
        const float v = st[ft][r] * scale;
        const int kvg = kvt * 64 + ft * 16 + g * 4 + r;
        sv[ft * 4 + r] = (kvg > qrow) ? -1e30f : v;
      }
    }
    float mt = sv[0];
#pragma unroll
    for (int i = 1; i < 16; ++i) mt = fmaxf(mt, sv[i]);
    mt = fmaxf(mt, __shfl_xor(mt, 16));
    mt = fmaxf(mt, __shfl_xor(mt, 32));
    const float mnew = fmaxf(mrun, mt);
    const float corr = __expf(mrun - mnew);
    float psum = 0.0f;
    unsigned int pw[8];
#pragma unroll
    for (int i = 0; i < 8; ++i) {
      const float p0 = __expf(sv[2 * i] - mnew);
      const float p1 = __expf(sv[2 * i + 1] - mnew);
      psum += p0 + p1;
      pw[i] = (unsigned)f2bf(p0) | ((unsigned)f2bf(p1) << 16);
    }
    psum += __shfl_xor(psum, 16);
    psum += __shfl_xor(psum, 32);
    lrun = lrun * corr + psum;
    mrun = mnew;

    // ---- P to per-wave LDS, b64-granule XOR layout:
    // granule value v (kv = 4v..4v+3) of row q=c stored at slot v^(c&15).
#pragma unroll
    for (int ft = 0; ft < 4; ++ft) {
      uint2 pk;
      pk.x = pw[2 * ft];
      pk.y = pw[2 * ft + 1];
      *(uint2*)(pbuf + c * 64 + (((ft * 4 + g) ^ (c & 15)) << 2)) = pk;
    }
    asm volatile("" ::: "memory");
    const bf16x4 p0 = *(const bf16x4*)(pbuf + c * 64 + (((2 * g) ^ (c & 15)) << 2));
    const bf16x4 p1 = *(const bf16x4*)(pbuf + c * 64 + (((2 * g + 1) ^ (c & 15)) << 2));
    const bf16x4 p2 = *(const bf16x4*)(pbuf + c * 64 + (((8 + 2 * g) ^ (c & 15)) << 2));
    const bf16x4 p3 = *(const bf16x4*)(pbuf + c * 64 + (((9 + 2 * g) ^ (c & 15)) << 2));
    const bf16x8 pa0 = __builtin_shufflevector(p0, p1, 0, 1, 2, 3, 4, 5, 6, 7);
    const bf16x8 pa1 = __builtin_shufflevector(p2, p3, 0, 1, 2, 3, 4, 5, 6, 7);

    // rescale O by corr (oacc rows are q = g*4 + r)
    float cr[4];
#pragma unroll
    for (int r = 0; r < 4; ++r) cr[r] = __shfl(corr, g * 4 + r);
#pragma unroll
    for (int dt = 0; dt < 32; ++dt) {
      oacc[dt][0] *= cr[0];
      oacc[dt][1] *= cr[1];
      oacc[dt][2] *= cr[2];
      oacc[dt][3] *= cr[3];
    }

    if (VG) {
      // ---- PV: V^T frags straight from global qkvT (coalesced, L2/L3-hot)
      const int kvoff = kvt * 128;
#pragma unroll
      for (int dt = 0; dt < 32; ++dt) {
        const char* p = vtb + (size_t)(dt * 16 + c) * 2048 + kvoff + (g << 4);
        const bf16x8 b0 = *(const bf16x8*)p;
        const bf16x8 b1 = *(const bf16x8*)(p + 64);
        oacc[dt] = MFMA(pa0, b0, oacc[dt]);
        oacc[dt] = MFMA(pa1, b1, oacc[dt]);
      }
    } else {
      // ---- PV: scalar strided reads from (swizzled) kvs
#pragma unroll
      for (int dt = 0; dt < 32; ++dt) {
        const int col = dt * 16 + c;
        bf16x8 b0, b1;
#pragma unroll
        for (int j = 0; j < 8; ++j) {
          const int gr = (((col >> 3) ^ j) << 4) + (col & 7) * 2;
          b0[j] = *(const short*)(kvs + (g * 8 + j) * 1024 + gr);
          b1[j] = *(const short*)(kvs + (32 + g * 8 + j) * 1024 + gr);
        }
        oacc[dt] = MFMA(pa0, b0, oacc[dt]);
        oacc[dt] = MFMA(pa1, b1, oacc[dt]);
      }
      __syncthreads();  // kvs reads (QK+PV) done -> restage safe
      if (kvt + 1 < nkv) {
        const char* tb = (const char*)(qkv + bcbase + (size_t)(kvt + 1) * 64 * DDIM);
#pragma unroll
        for (int r = 0; r < 8; ++r)
          async_load16(tb + soff[r], kvs + r * 8192 + (wid << 10));
      }
    }
  }

  // ---- epilogue: x + O/l
  const float rl = 1.0f / lrun;
  float rlr[4];
#pragma unroll
  for (int r = 0; r < 4; ++r) rlr[r] = __shfl(rl, g * 4 + r);
#pragma unroll
  for (int dt = 0; dt < 32; ++dt) {
#pragma unroll
    for (int r = 0; r < 4; ++r) {
      const size_t off =
          bcbase + (size_t)(qt * 128 + wid * 16 + g * 4 + r) * DDIM + dt * 16 + c;
      xo[off] = x[off] + oacc[dt][r] * rlr[r];
    }
  }
}

// ---------------- cell mixing + sin pulse (in-place on d_out) ----------------
__global__ __launch_bounds__(256) void k_mix(float* __restrict__ xo,
                                             const float* __restrict__ inh,
                                             const float* __restrict__ phz,
                                             const float* __restrict__ rsc) {
  __shared__ float sI[256];
  __shared__ float sP[16];
  const int tid = threadIdx.x;
  sI[tid] = inh[tid];
  if (tid < 16) sP[tid] = phz[tid];
  __syncthreads();
  const float rs = rsc[0];
  const int idx = blockIdx.x * 256 + tid;
  const int d4 = idx & 127;
  const int t = (idx >> 7) & 1023;
  const int b = idx >> 17;
  float4* base = (float4*)xo + ((size_t)b * 16 * TSEQ + t) * 128 + d4;
  float4 v[16];
#pragma unroll
  for (int cc = 0; cc < 16; ++cc) v[cc] = base[(size_t)cc * TSEQ * 128];
#pragma unroll
  for (int k = 0; k < 16; ++k) {
    float4 comp = make_float4(0.f, 0.f, 0.f, 0.f);
#pragma unroll
    for (int cc = 0; cc < 16; ++cc) {
      const float w = sI[cc * 16 + k];
      comp.x += v[cc].x * w;
      comp.y += v[cc].y * w;
      comp.z += v[cc].z * w;
      comp.w += v[cc].w * w;
    }
    const float ph = sP[k];
    float4 o;
    o.x = v[k].x + __sinf(comp.x + ph) * rs;
    o.y = v[k].y + __sinf(comp.y + ph) * rs;
    o.z = v[k].z + __sinf(comp.z + ph) * rs;
    o.w = v[k].w + __sinf(comp.w + ph) * rs;
    base[(size_t)k * TSEQ * 128] = o;
  }
}

extern "C" void kernel_launch(void* const* d_in, const int* in_sizes, int n_in,
                              void* d_out, int out_size, void* d_ws, size_t ws_size,
                              hipStream_t stream) {
  const float* x = (const float*)d_in[0];
  // d_in[1] = causal mask -- implemented analytically
  const float* gamma = (const float*)d_in[2];
  const float* beta = (const float*)d_in[3];
  const float* Wg = (const float*)d_in[4];
  const float* inh = (const float*)d_in[5];
  const float* phz = (const float*)d_in[6];
  const float* rsc = (const float*)d_in[7];
  float* out = (float*)d_out;

  // ws: qkv (64MiB) [+ qkvT (64MiB) if it fits]. nx -> d_out[0:64MiB);
  // wgb -> d_out tail (byte 100MiB). k_attn/k_mix later overwrite all of
  // d_out with the real output.
  unsigned short* qkv = (unsigned short*)d_ws;
  unsigned short* qkvT = qkv + (size_t)33554432;
  unsigned short* nx = (unsigned short*)d_out;
  unsigned short* wgb = (unsigned short*)((char*)d_out + 104857600);
  const bool big = ws_size >= 134217728ull;

  k_cast<<<128, 256, 0, stream>>>(Wg, wgb, 32768);
  k_ln<<<16384, 256, 0, stream>>>(x, gamma, beta, nx);
  k_gemm<<<dim3(4, 512), 256, 0, stream>>>(nx, wgb, qkv);
  if (big) {
    k_vt<<<dim3(16, 8, 64), 256, 0, stream>>>(qkv, qkvT);
    k_attn<1><<<dim3(64, 8), 512, 0, stream>>>(qkv, qkvT, x, out);
  } else {
    k_attn<0><<<dim3(64, 8), 512, 0, stream>>>(qkv, qkv, x, out);
  }
  k_mix<<<2048, 256, 0, stream>>>(out, inh, phz, rsc);
}

// Round 5
// 546.121 us; speedup vs baseline: 1.1731x; 1.0757x over previous
//
#include <hip/hip_runtime.h>
#include <stdint.h>

#define TSEQ 1024
#define DDIM 512

typedef __attribute__((ext_vector_type(8))) short bf16x8;
typedef __attribute__((ext_vector_type(4))) float f32x4;

#define MFMA(a, b, c) __builtin_amdgcn_mfma_f32_16x16x32_bf16((a), (b), (c), 0, 0, 0)

__device__ __forceinline__ unsigned short f2bf(float f) {
  unsigned int u = __builtin_bit_cast(unsigned int, f);
  u += 0x7FFFu + ((u >> 16) & 1u);
  return (unsigned short)(u >> 16);
}

__device__ __forceinline__ void async_load16(const void* g, void* l) {
  __builtin_amdgcn_global_load_lds(
      (const __attribute__((address_space(1))) unsigned int*)g,
      (__attribute__((address_space(3))) unsigned int*)l, 16, 0, 0);
}

// ---------------- LayerNorm: x[65536][512] f32 -> nx bf16 ----------------
__global__ __launch_bounds__(256) void k_ln(const float* __restrict__ x,
                                            const float* __restrict__ gamma,
                                            const float* __restrict__ beta,
                                            unsigned short* __restrict__ nx) {
  const int wid = threadIdx.x >> 6, lane = threadIdx.x & 63;
  const long long row = (long long)blockIdx.x * 4 + wid;
  const float* xr = x + row * DDIM + lane * 8;
  float4 a = *(const float4*)xr;
  float4 b = *(const float4*)(xr + 4);
  float s = a.x + a.y + a.z + a.w + b.x + b.y + b.z + b.w;
  float s2 = a.x * a.x + a.y * a.y + a.z * a.z + a.w * a.w +
             b.x * b.x + b.y * b.y + b.z * b.z + b.w * b.w;
#pragma unroll
  for (int m = 1; m < 64; m <<= 1) {
    s += __shfl_xor(s, m);
    s2 += __shfl_xor(s2, m);
  }
  const float mu = s * (1.0f / DDIM);
  const float var = s2 * (1.0f / DDIM) - mu * mu;
  const float rsd = rsqrtf(var + 1e-5f);
  const float4 g0 = *(const float4*)(gamma + lane * 8);
  const float4 g1 = *(const float4*)(gamma + lane * 8 + 4);
  const float4 b0 = *(const float4*)(beta + lane * 8);
  const float4 b1 = *(const float4*)(beta + lane * 8 + 4);
  float o0 = (a.x - mu) * rsd * g0.x + b0.x;
  float o1 = (a.y - mu) * rsd * g0.y + b0.y;
  float o2 = (a.z - mu) * rsd * g0.z + b0.z;
  float o3 = (a.w - mu) * rsd * g0.w + b0.w;
  float o4 = (b.x - mu) * rsd * g1.x + b1.x;
  float o5 = (b.y - mu) * rsd * g1.y + b1.y;
  float o6 = (b.z - mu) * rsd * g1.z + b1.z;
  float o7 = (b.w - mu) * rsd * g1.w + b1.w;
  uint4 pk;
  pk.x = f2bf(o0) | ((unsigned)f2bf(o1) << 16);
  pk.y = f2bf(o2) | ((unsigned)f2bf(o3) << 16);
  pk.z = f2bf(o4) | ((unsigned)f2bf(o5) << 16);
  pk.w = f2bf(o6) | ((unsigned)f2bf(o7) << 16);
  *(uint4*)(nx + row * DDIM + lane * 8) = pk;
}

// ---------------- cast Wg f32 -> bf16 ----------------
__global__ __launch_bounds__(256) void k_cast(const float* __restrict__ w,
                                              unsigned short* __restrict__ o, int n8) {
  const int i = blockIdx.x * 256 + threadIdx.x;
  if (i >= n8) return;
  const float4 a = *(const float4*)(w + (size_t)i * 8);
  const float4 b = *(const float4*)(w + (size_t)i * 8 + 4);
  uint4 pk;
  pk.x = f2bf(a.x) | ((unsigned)f2bf(a.y) << 16);
  pk.y = f2bf(a.z) | ((unsigned)f2bf(a.w) << 16);
  pk.z = f2bf(b.x) | ((unsigned)f2bf(b.y) << 16);
  pk.w = f2bf(b.z) | ((unsigned)f2bf(b.w) << 16);
  *(uint4*)(o + (size_t)i * 8) = pk;
}

// ---------------- GEMM: qkv[M][512] = nx[M][512] @ Wg[512][512]^T ----------
// m97 structure (unchanged, verified R1-R4).
__global__ __launch_bounds__(256, 2) void k_gemm(const unsigned short* __restrict__ A,
                                                 const unsigned short* __restrict__ B,
                                                 unsigned short* __restrict__ C) {
  __shared__ char As[16384];
  __shared__ char Bs[16384];
  const int tid = threadIdx.x;
  const int wid = tid >> 6, lane = tid & 63;
  const int g = lane >> 4, c = lane & 15;
  const int wr = wid >> 1, wc = wid & 1;
  const int bm = blockIdx.y, bn = blockIdx.x;

  int srcoff[4], ldsoff[4];
#pragma unroll
  for (int r = 0; r < 4; ++r) {
    const int aoff = r * 4096 + tid * 16;
    srcoff[r] = (aoff >> 7) * 1024 + (aoff & 127);
    ldsoff[r] = r * 4096 + (wid << 10);
  }
  const char* Ab = (const char*)A + (size_t)bm * 131072;
  const char* Bb = (const char*)B + (size_t)bn * 131072;

  f32x4 acc[4][4] = {};

  for (int ks = 0; ks < 8; ++ks) {
    __syncthreads();
#pragma unroll
    for (int r = 0; r < 4; ++r) {
      async_load16(Ab + ks * 128 + srcoff[r], As + ldsoff[r]);
      async_load16(Bb + ks * 128 + srcoff[r], Bs + ldsoff[r]);
    }
    __syncthreads();
    bf16x8 af[4][2], bfr[4][2];
#pragma unroll
    for (int f = 0; f < 4; ++f) {
#pragma unroll
      for (int kk = 0; kk < 2; ++kk) {
        const int rowa = wr * 64 + f * 16 + c;
        af[f][kk] = *(const bf16x8*)(As + rowa * 128 + (kk * 4 + g) * 16);
        const int rowb = wc * 64 + f * 16 + c;
        bfr[f][kk] = *(const bf16x8*)(Bs + rowb * 128 + (kk * 4 + g) * 16);
      }
    }
#pragma unroll
    for (int i = 0; i < 4; ++i) {
#pragma unroll
      for (int j = 0; j < 4; ++j) {
        acc[i][j] = MFMA(af[i][0], bfr[j][0], acc[i][j]);
        acc[i][j] = MFMA(af[i][1], bfr[j][1], acc[i][j]);
      }
    }
  }
#pragma unroll
  for (int i = 0; i < 4; ++i) {
#pragma unroll
    for (int r = 0; r < 4; ++r) {
      const long long row = (long long)bm * 128 + wr * 64 + i * 16 + g * 4 + r;
#pragma unroll
      for (int j = 0; j < 4; ++j) {
        const int col = bn * 128 + wc * 64 + j * 16 + c;
        C[row * DDIM + col] = f2bf(acc[i][j][r]);
      }
    }
  }
}

// ---------------- qkv [bc][t][d] -> qkvT [bc][d][t] (tiled transpose) -------
__global__ __launch_bounds__(256) void k_vt(const unsigned short* __restrict__ qkv,
                                            unsigned short* __restrict__ qkvT) {
  __shared__ unsigned short t[64][72];
  const int ti = blockIdx.x;
  const int di = blockIdx.y;
  const int bc = blockIdx.z;
  const int tid = threadIdx.x;
  const int r = tid >> 3, c8 = tid & 7;
  const unsigned short* src = qkv + ((size_t)bc * TSEQ + ti * 64) * DDIM + di * 64;
#pragma unroll
  for (int p = 0; p < 2; ++p) {
    const bf16x8 v = *(const bf16x8*)(src + (size_t)(r + p * 32) * DDIM + c8 * 8);
    *(bf16x8*)&t[r + p * 32][c8 * 8] = v;
  }
  __syncthreads();
  unsigned short* dst = qkvT + ((size_t)bc * DDIM + di * 64) * TSEQ + ti * 64;
#pragma unroll
  for (int p = 0; p < 2; ++p) {
    const int d = r + p * 32;
    bf16x8 v;
#pragma unroll
    for (int j = 0; j < 8; ++j) v[j] = t[c8 * 8 + j][d];
    *(bf16x8*)(dst + (size_t)d * TSEQ + c8 * 8) = v;
  }
}

// ---------------- Flash attention (causal), Q=K=V=qkv, + residual add --------
// R5: permuted-K QK^T so P lands in-register in PV A-frag layout (no P-LDS,
// no shuffles). K LDS double-buffered (2x64KiB), ONE barrier per tile,
// stage(t+1) issued right after it. kappa(row)=(row&7)^(((row>>3)&3)<<1)
// 16B-granule XOR swizzle on both staging source and reads. PV B-frags from
// global qkvT (verified R4). Rescale skipped when wave-uniformly corr==1.
__global__ __launch_bounds__(512, 2) void k_attn(const unsigned short* __restrict__ qkv,
                                                 const unsigned short* __restrict__ qkvT,
                                                 const float* __restrict__ x,
                                                 float* __restrict__ xo) {
  __shared__ char kvs2[2][65536];
  const int tid = threadIdx.x;
  const int wid = tid >> 6, lane = tid & 63;
  const int g = lane >> 4, c = lane & 15;
  const int bc = blockIdx.x;
  const int qt = 7 - blockIdx.y;  // heavy q-tiles dispatch first
  const size_t bcbase = (size_t)bc * TSEQ * DDIM;
  const int qrow = qt * 128 + wid * 16 + c;

  // Q fragments: lane holds Q[q = c][d = ks*32 + g*8 + j]
  bf16x8 qf[16];
  const unsigned short* qp = qkv + bcbase + (size_t)qrow * DDIM + g * 8;
#pragma unroll
  for (int ks = 0; ks < 16; ++ks) qf[ks] = *(const bf16x8*)(qp + ks * 32);

  // K-read base offsets: row(ft,c) = (ft&1)*32 + (c>>2)*8 + (ft>>1)*4 + (c&3)
  // (row permutation chosen so st[ft][r] = S[(ft&1)*32 + g*8 + (ft>>1)*4 + r][c],
  //  i.e. PV A-frags come out in-register). kappa = (row&7)^(((row>>3)&3)<<1).
  int e0[4], e1[4];
#pragma unroll
  for (int ft = 0; ft < 4; ++ft) {
    const int row = (ft & 1) * 32 + ((c >> 2) << 3) + ((ft >> 1) << 2) + (c & 3);
    const int kap = (row & 7) ^ (((row >> 3) & 3) << 1);
    e0[ft] = row * 1024 + ((g ^ kap) << 4);
    e1[ft] = row * 1024 + (((4 + g) ^ kap) << 4);
  }

  // staging: linear LDS slot (row = r*8+wid, granule = lane) <- global granule
  // (lane ^ kappa(row)); kappa(r*8+wid) = wid ^ ((r&3)<<1)
  int soff[8];
#pragma unroll
  for (int r = 0; r < 8; ++r)
    soff[r] = (r * 8 + wid) * 1024 + ((lane ^ wid ^ ((r & 3) << 1)) << 4);

  f32x4 oacc[32] = {};
  float mrun = -1e30f, lrun = 0.0f;
  const float scale = 0.044194173824159216f;  // 512^-0.5
  const int nkv = 2 * qt + 2;

  {  // prologue: stage tile 0 -> buf 0
    const char* tb = (const char*)(qkv + bcbase);
#pragma unroll
    for (int r = 0; r < 8; ++r)
      async_load16(tb + soff[r], kvs2[0] + r * 8192 + (wid << 10));
  }

  const char* vtb = (const char*)qkvT + ((size_t)bc << 20);

  for (int kvt = 0; kvt < nkv; ++kvt) {
    __syncthreads();  // buf[kvt&1] staged (compiler drains vmcnt before barrier)
    const char* kb = kvs2[kvt & 1];

    if (kvt + 1 < nkv) {  // stage next tile into the other buffer
      const char* tb = (const char*)(qkv + bcbase + (size_t)(kvt + 1) * 64 * DDIM);
      char* db = kvs2[(kvt + 1) & 1];
#pragma unroll
      for (int r = 0; r < 8; ++r) async_load16(tb + soff[r], db + r * 8192 + (wid << 10));
    }

    // ---- QK^T (swapped, permuted rows)
    f32x4 st[4] = {};
    __builtin_amdgcn_s_setprio(1);
#pragma unroll
    for (int ks = 0; ks < 16; ++ks) {
      const int imm = (ks >> 1) * 128;
#pragma unroll
      for (int ft = 0; ft < 4; ++ft) {
        const bf16x8 kf =
            *(const bf16x8*)(kb + imm + ((ks & 1) ? e1[ft] : e0[ft]));
        st[ft] = MFMA(kf, qf[ks], st[ft]);
      }
    }
    __builtin_amdgcn_s_setprio(0);

    // ---- online softmax; lane (g,c) holds S[kv=(ft&1)*32+g*8+(ft>>1)*4+r][q=c]
    float ex[4][4];
    float mt = -1e30f;
#pragma unroll
    for (int ft = 0; ft < 4; ++ft) {
#pragma unroll
      for (int r = 0; r < 4; ++r) {
        const int kvg = kvt * 64 + (ft & 1) * 32 + g * 8 + ((ft >> 1) << 2) + r;
        const float v = st[ft][r] * scale;
        ex[ft][r] = (kvg > qrow) ? -1e30f : v;
        mt = fmaxf(mt, ex[ft][r]);
      }
    }
    mt = fmaxf(mt, __shfl_xor(mt, 16));
    mt = fmaxf(mt, __shfl_xor(mt, 32));
    const float mprev = mrun;
    const float mnew = fmaxf(mprev, mt);
    mrun = mnew;
    float psum = 0.0f;
#pragma unroll
    for (int ft = 0; ft < 4; ++ft) {
#pragma unroll
      for (int r = 0; r < 4; ++r) {
        ex[ft][r] = __expf(ex[ft][r] - mnew);
        psum += ex[ft][r];
      }
    }
    psum += __shfl_xor(psum, 16);
    psum += __shfl_xor(psum, 32);

    if (!__all(mt <= mprev)) {  // some q-row's max grew -> rescale O
      const float corr = __expf(mprev - mnew);
      lrun = lrun * corr + psum;
      float cr[4];
#pragma unroll
      for (int r = 0; r < 4; ++r) cr[r] = __shfl(corr, g * 4 + r);
#pragma unroll
      for (int dt = 0; dt < 32; ++dt) {
        oacc[dt][0] *= cr[0];
        oacc[dt][1] *= cr[1];
        oacc[dt][2] *= cr[2];
        oacc[dt][3] *= cr[3];
      }
    } else {
      lrun += psum;
    }

    // ---- P A-frags in-register: pa0[j] = P[q=c][kv=g*8+j], pa1: kv=32+g*8+j
    bf16x8 pa0, pa1;
#pragma unroll
    for (int r = 0; r < 4; ++r) {
      pa0[r] = (short)f2bf(ex[0][r]);
      pa0[r + 4] = (short)f2bf(ex[2][r]);
      pa1[r] = (short)f2bf(ex[1][r]);
      pa1[r + 4] = (short)f2bf(ex[3][r]);
    }

    // ---- PV: V^T frags from global qkvT (16 rows x 64B per wave-instr)
    const char* vp = vtb + (size_t)c * 2048 + kvt * 128 + (g << 4);
#pragma unroll
    for (int dt = 0; dt < 32; ++dt) {
      const bf16x8 b0 = *(const bf16x8*)(vp + dt * 32768);
      const bf16x8 b1 = *(const bf16x8*)(vp + dt * 32768 + 64);
      oacc[dt] = MFMA(pa0, b0, oacc[dt]);
      oacc[dt] = MFMA(pa1, b1, oacc[dt]);
    }
  }

  // ---- epilogue: x + O/l  (oacc[dt][r] = O[q=g*4+r][d=dt*16+c])
  const float rl = 1.0f / lrun;
  float rlr[4];
#pragma unroll
  for (int r = 0; r < 4; ++r) rlr[r] = __shfl(rl, g * 4 + r);
#pragma unroll
  for (int dt = 0; dt < 32; ++dt) {
#pragma unroll
    for (int r = 0; r < 4; ++r) {
      const size_t off =
          bcbase + (size_t)(qt * 128 + wid * 16 + g * 4 + r) * DDIM + dt * 16 + c;
      xo[off] = x[off] + oacc[dt][r] * rlr[r];
    }
  }
}

// ---------------- cell mixing + sin pulse (in-place on d_out) ----------------
__global__ __launch_bounds__(256) void k_mix(float* __restrict__ xo,
                                             const float* __restrict__ inh,
                                             const float* __restrict__ phz,
                                             const float* __restrict__ rsc) {
  __shared__ float sI[256];
  __shared__ float sP[16];
  const int tid = threadIdx.x;
  sI[tid] = inh[tid];
  if (tid < 16) sP[tid] = phz[tid];
  __syncthreads();
  const float rs = rsc[0];
  const int idx = blockIdx.x * 256 + tid;
  const int d4 = idx & 127;
  const int t = (idx >> 7) & 1023;
  const int b = idx >> 17;
  float4* base = (float4*)xo + ((size_t)b * 16 * TSEQ + t) * 128 + d4;
  float4 v[16];
#pragma unroll
  for (int cc = 0; cc < 16; ++cc) v[cc] = base[(size_t)cc * TSEQ * 128];
#pragma unroll
  for (int k = 0; k < 16; ++k) {
    float4 comp = make_float4(0.f, 0.f, 0.f, 0.f);
#pragma unroll
    for (int cc = 0; cc < 16; ++cc) {
      const float w = sI[cc * 16 + k];
      comp.x += v[cc].x * w;
      comp.y += v[cc].y * w;
      comp.z += v[cc].z * w;
      comp.w += v[cc].w * w;
    }
    const float ph = sP[k];
    float4 o;
    o.x = v[k].x + __sinf(comp.x + ph) * rs;
    o.y = v[k].y + __sinf(comp.y + ph) * rs;
    o.z = v[k].z + __sinf(comp.z + ph) * rs;
    o.w = v[k].w + __sinf(comp.w + ph) * rs;
    base[(size_t)k * TSEQ * 128] = o;
  }
}

extern "C" void kernel_launch(void* const* d_in, const int* in_sizes, int n_in,
                              void* d_out, int out_size, void* d_ws, size_t ws_size,
                              hipStream_t stream) {
  const float* x = (const float*)d_in[0];
  // d_in[1] = causal mask -- implemented analytically
  const float* gamma = (const float*)d_in[2];
  const float* beta = (const float*)d_in[3];
  const float* Wg = (const float*)d_in[4];
  const float* inh = (const float*)d_in[5];
  const float* phz = (const float*)d_in[6];
  const float* rsc = (const float*)d_in[7];
  float* out = (float*)d_out;

  // ws (>=128MiB, confirmed R3/R4): qkv (64MiB) + qkvT (64MiB).
  // nx -> d_out[0:64MiB); wgb -> d_out @100MiB (both dead before k_attn's
  // writes land).
  unsigned short* qkv = (unsigned short*)d_ws;
  unsigned short* qkvT = qkv + (size_t)33554432;
  unsigned short* nx = (unsigned short*)d_out;
  unsigned short* wgb = (unsigned short*)((char*)d_out + 104857600);

  k_cast<<<128, 256, 0, stream>>>(Wg, wgb, 32768);
  k_ln<<<16384, 256, 0, stream>>>(x, gamma, beta, nx);
  k_gemm<<<dim3(4, 512), 256, 0, stream>>>(nx, wgb, qkv);
  k_vt<<<dim3(16, 8, 64), 256, 0, stream>>>(qkv, qkvT);
  k_attn<<<dim3(64, 8), 512, 0, stream>>>(qkv, qkvT, x, out);
  k_mix<<<2048, 256, 0, stream>>>(out, inh, phz, rsc);
}

// Round 6
// 350.398 us; speedup vs baseline: 1.8284x; 1.5586x over previous
//
#include <hip/hip_runtime.h>
#include <stdint.h>

#define TSEQ 1024
#define DDIM 512

typedef __attribute__((ext_vector_type(8))) short bf16x8;
typedef __attribute__((ext_vector_type(4))) float f32x4;

#define MFMA(a, b, c) __builtin_amdgcn_mfma_f32_16x16x32_bf16((a), (b), (c), 0, 0, 0)

__device__ __forceinline__ unsigned short f2bf(float f) {
  unsigned int u = __builtin_bit_cast(unsigned int, f);
  u += 0x7FFFu + ((u >> 16) & 1u);
  return (unsigned short)(u >> 16);
}

__device__ __forceinline__ void async_load16(const void* g, void* l) {
  __builtin_amdgcn_global_load_lds(
      (const __attribute__((address_space(1))) unsigned int*)g,
      (__attribute__((address_space(3))) unsigned int*)l, 16, 0, 0);
}

// ---------------- LayerNorm: x[65536][512] f32 -> nx bf16 ----------------
__global__ __launch_bounds__(256) void k_ln(const float* __restrict__ x,
                                            const float* __restrict__ gamma,
                                            const float* __restrict__ beta,
                                            unsigned short* __restrict__ nx) {
  const int wid = threadIdx.x >> 6, lane = threadIdx.x & 63;
  const long long row = (long long)blockIdx.x * 4 + wid;
  const float* xr = x + row * DDIM + lane * 8;
  float4 a = *(const float4*)xr;
  float4 b = *(const float4*)(xr + 4);
  float s = a.x + a.y + a.z + a.w + b.x + b.y + b.z + b.w;
  float s2 = a.x * a.x + a.y * a.y + a.z * a.z + a.w * a.w +
             b.x * b.x + b.y * b.y + b.z * b.z + b.w * b.w;
#pragma unroll
  for (int m = 1; m < 64; m <<= 1) {
    s += __shfl_xor(s, m);
    s2 += __shfl_xor(s2, m);
  }
  const float mu = s * (1.0f / DDIM);
  const float var = s2 * (1.0f / DDIM) - mu * mu;
  const float rsd = rsqrtf(var + 1e-5f);
  const float4 g0 = *(const float4*)(gamma + lane * 8);
  const float4 g1 = *(const float4*)(gamma + lane * 8 + 4);
  const float4 b0 = *(const float4*)(beta + lane * 8);
  const float4 b1 = *(const float4*)(beta + lane * 8 + 4);
  float o0 = (a.x - mu) * rsd * g0.x + b0.x;
  float o1 = (a.y - mu) * rsd * g0.y + b0.y;
  float o2 = (a.z - mu) * rsd * g0.z + b0.z;
  float o3 = (a.w - mu) * rsd * g0.w + b0.w;
  float o4 = (b.x - mu) * rsd * g1.x + b1.x;
  float o5 = (b.y - mu) * rsd * g1.y + b1.y;
  float o6 = (b.z - mu) * rsd * g1.z + b1.z;
  float o7 = (b.w - mu) * rsd * g1.w + b1.w;
  uint4 pk;
  pk.x = f2bf(o0) | ((unsigned)f2bf(o1) << 16);
  pk.y = f2bf(o2) | ((unsigned)f2bf(o3) << 16);
  pk.z = f2bf(o4) | ((unsigned)f2bf(o5) << 16);
  pk.w = f2bf(o6) | ((unsigned)f2bf(o7) << 16);
  *(uint4*)(nx + row * DDIM + lane * 8) = pk;
}

// ---------------- cast Wg f32 -> bf16 ----------------
__global__ __launch_bounds__(256) void k_cast(const float* __restrict__ w,
                                              unsigned short* __restrict__ o, int n8) {
  const int i = blockIdx.x * 256 + threadIdx.x;
  if (i >= n8) return;
  const float4 a = *(const float4*)(w + (size_t)i * 8);
  const float4 b = *(const float4*)(w + (size_t)i * 8 + 4);
  uint4 pk;
  pk.x = f2bf(a.x) | ((unsigned)f2bf(a.y) << 16);
  pk.y = f2bf(a.z) | ((unsigned)f2bf(a.w) << 16);
  pk.z = f2bf(b.x) | ((unsigned)f2bf(b.y) << 16);
  pk.w = f2bf(b.z) | ((unsigned)f2bf(b.w) << 16);
  *(uint4*)(o + (size_t)i * 8) = pk;
}

// ---------------- GEMM: qkv[M][512] = nx[M][512] @ Wg[512][512]^T ----------
// m97 structure (unchanged, verified R1-R5).
__global__ __launch_bounds__(256, 2) void k_gemm(const unsigned short* __restrict__ A,
                                                 const unsigned short* __restrict__ B,
                                                 unsigned short* __restrict__ C) {
  __shared__ char As[16384];
  __shared__ char Bs[16384];
  const int tid = threadIdx.x;
  const int wid = tid >> 6, lane = tid & 63;
  const int g = lane >> 4, c = lane & 15;
  const int wr = wid >> 1, wc = wid & 1;
  const int bm = blockIdx.y, bn = blockIdx.x;

  int srcoff[4], ldsoff[4];
#pragma unroll
  for (int r = 0; r < 4; ++r) {
    const int aoff = r * 4096 + tid * 16;
    srcoff[r] = (aoff >> 7) * 1024 + (aoff & 127);
    ldsoff[r] = r * 4096 + (wid << 10);
  }
  const char* Ab = (const char*)A + (size_t)bm * 131072;
  const char* Bb = (const char*)B + (size_t)bn * 131072;

  f32x4 acc[4][4] = {};

  for (int ks = 0; ks < 8; ++ks) {
    __syncthreads();
#pragma unroll
    for (int r = 0; r < 4; ++r) {
      async_load16(Ab + ks * 128 + srcoff[r], As + ldsoff[r]);
      async_load16(Bb + ks * 128 + srcoff[r], Bs + ldsoff[r]);
    }
    __syncthreads();
    bf16x8 af[4][2], bfr[4][2];
#pragma unroll
    for (int f = 0; f < 4; ++f) {
#pragma unroll
      for (int kk = 0; kk < 2; ++kk) {
        const int rowa = wr * 64 + f * 16 + c;
        af[f][kk] = *(const bf16x8*)(As + rowa * 128 + (kk * 4 + g) * 16);
        const int rowb = wc * 64 + f * 16 + c;
        bfr[f][kk] = *(const bf16x8*)(Bs + rowb * 128 + (kk * 4 + g) * 16);
      }
    }
#pragma unroll
    for (int i = 0; i < 4; ++i) {
#pragma unroll
      for (int j = 0; j < 4; ++j) {
        acc[i][j] = MFMA(af[i][0], bfr[j][0], acc[i][j]);
        acc[i][j] = MFMA(af[i][1], bfr[j][1], acc[i][j]);
      }
    }
  }
#pragma unroll
  for (int i = 0; i < 4; ++i) {
#pragma unroll
    for (int r = 0; r < 4; ++r) {
      const long long row = (long long)bm * 128 + wr * 64 + i * 16 + g * 4 + r;
#pragma unroll
      for (int j = 0; j < 4; ++j) {
        const int col = bn * 128 + wc * 64 + j * 16 + c;
        C[row * DDIM + col] = f2bf(acc[i][j][r]);
      }
    }
  }
}

// ---------------- qkv [bc][t][d] -> qkvT [bc][d][t] (tiled transpose) -------
__global__ __launch_bounds__(256) void k_vt(const unsigned short* __restrict__ qkv,
                                            unsigned short* __restrict__ qkvT) {
  __shared__ unsigned short t[64][72];
  const int ti = blockIdx.x;
  const int di = blockIdx.y;
  const int bc = blockIdx.z;
  const int tid = threadIdx.x;
  const int r = tid >> 3, c8 = tid & 7;
  const unsigned short* src = qkv + ((size_t)bc * TSEQ + ti * 64) * DDIM + di * 64;
#pragma unroll
  for (int p = 0; p < 2; ++p) {
    const bf16x8 v = *(const bf16x8*)(src + (size_t)(r + p * 32) * DDIM + c8 * 8);
    *(bf16x8*)&t[r + p * 32][c8 * 8] = v;
  }
  __syncthreads();
  unsigned short* dst = qkvT + ((size_t)bc * DDIM + di * 64) * TSEQ + ti * 64;
#pragma unroll
  for (int p = 0; p < 2; ++p) {
    const int d = r + p * 32;
    bf16x8 v;
#pragma unroll
    for (int j = 0; j < 8; ++j) v[j] = t[c8 * 8 + j][d];
    *(bf16x8*)(dst + (size_t)d * TSEQ + c8 * 8) = v;
  }
}

// ---------------- Flash attention (causal), Q=K=V=qkv, + residual add --------
// R6: KVB=32; K (2x32K, kappa-swizzled) AND V^T (2x32K, from qkvT, no swizzle
// needed: 64B rows alternate bank halves) both double-buffered in 128KiB LDS.
// One barrier per tile; stage(t+1) right after it. PV = 32 ds_read_b128 off
// one base reg + imm (zero vmem in loop). P in-register (permuted-K, 2-ft).
// Each block does q-tile pair (7-qy, qy): all blocks = 36 tiles, grid=256=1/CU.
__global__ __launch_bounds__(512, 2) void k_attn(const unsigned short* __restrict__ qkv,
                                                 const unsigned short* __restrict__ qkvT,
                                                 const float* __restrict__ x,
                                                 float* __restrict__ xo) {
  __shared__ char lds[131072];  // [0,64K): K dbuf; [64K,128K): VT dbuf
  const int tid = threadIdx.x;
  const int wid = tid >> 6, lane = tid & 63;
  const int g = lane >> 4, c = lane & 15;
  const int bc = blockIdx.x;
  const size_t bcbase = (size_t)bc * TSEQ * DDIM;
  const float scale = 0.044194173824159216f;  // 512^-0.5

  // QK K-read offsets: row(ft,c) = (c>>2)*8 + ft*4 + (c&3), ft in {0,1};
  // kappa = ((ft<<2)|(c&3)) ^ ((c>>2)<<1). (P lands in-register: lane (g,c)
  // gets S[kv = g*8 + ft*4 + r][q = c].)
  int e0[2], e1[2];
#pragma unroll
  for (int ft = 0; ft < 2; ++ft) {
    const int row = ((c >> 2) << 3) + (ft << 2) + (c & 3);
    const int kap = ((ft << 2) | (c & 3)) ^ ((c >> 2) << 1);
    e0[ft] = row * 1024 + ((g ^ kap) << 4);
    e1[ft] = row * 1024 + (((4 + g) ^ kap) << 4);
  }

  // staging offsets (wave wid covers K rows wid*4+r / VT d-rows wid*64+r*16+..)
  int soffK[4], soffV[4];
#pragma unroll
  for (int r = 0; r < 4; ++r) {
    const int row = wid * 4 + r;
    const int kap = (row & 7) ^ (((row >> 3) & 3) << 1);
    soffK[r] = row * 1024 + ((lane ^ kap) << 4);
    soffV[r] = (wid * 64 + r * 16 + (lane >> 2)) * 2048 + (lane & 3) * 16;
  }
  const char* kgb = (const char*)(qkv + bcbase);
  const char* vgb = (const char*)qkvT + ((size_t)bc << 20);

#pragma unroll 1
  for (int h = 0; h < 2; ++h) {
    const int qt = h == 0 ? 7 - blockIdx.y : blockIdx.y;
    const int qrow = qt * 128 + wid * 16 + c;
    const int NT = 4 * qt + 4;

    // Q fragments: lane holds Q[q = c][d = ks*32 + g*8 + j]
    bf16x8 qf[16];
    const unsigned short* qp = qkv + bcbase + (size_t)qrow * DDIM + g * 8;
#pragma unroll
    for (int ks = 0; ks < 16; ++ks) qf[ks] = *(const bf16x8*)(qp + ks * 32);

    f32x4 oacc[32] = {};
    float mrun = -1e30f, lrun = 0.0f;

    {  // prologue: stage tile 0 -> buf 0
      char* kb = lds;
      char* vb = lds + 65536;
#pragma unroll
      for (int r = 0; r < 4; ++r) {
        async_load16(kgb + soffK[r], kb + wid * 4096 + r * 1024 + lane * 16);
        async_load16(vgb + soffV[r], vb + wid * 4096 + r * 1024 + lane * 16);
      }
    }

    for (int kvt = 0; kvt < NT; ++kvt) {
      __syncthreads();  // buf[kvt&1] staged (barrier drains own vmcnt)
      const char* kb = lds + (kvt & 1) * 32768;
      const char* vb = lds + 65536 + (kvt & 1) * 32768;

      if (kvt + 1 < NT) {  // stage next into other buffer; hides under compute
        char* kd = lds + ((kvt + 1) & 1) * 32768;
        char* vd = lds + 65536 + ((kvt + 1) & 1) * 32768;
        const char* ksrc = kgb + (kvt + 1) * 32768;
        const char* vsrc = vgb + (kvt + 1) * 64;
#pragma unroll
        for (int r = 0; r < 4; ++r) {
          async_load16(ksrc + soffK[r], kd + wid * 4096 + r * 1024 + lane * 16);
          async_load16(vsrc + soffV[r], vd + wid * 4096 + r * 1024 + lane * 16);
        }
      }

      // ---- QK^T (swapped, permuted rows): 32 MFMA
      f32x4 st[2] = {};
      __builtin_amdgcn_s_setprio(1);
#pragma unroll
      for (int ks = 0; ks < 16; ++ks) {
        const int imm = (ks >> 1) * 128;
#pragma unroll
        for (int ft = 0; ft < 2; ++ft) {
          const bf16x8 kf = *(const bf16x8*)(kb + imm + ((ks & 1) ? e1[ft] : e0[ft]));
          st[ft] = MFMA(kf, qf[ks], st[ft]);
        }
      }
      __builtin_amdgcn_s_setprio(0);

      // ---- online softmax; lane holds S[kv = g*8 + ft*4 + r][q = c]
      float ex[2][4];
      float mt = -1e30f;
#pragma unroll
      for (int ft = 0; ft < 2; ++ft) {
#pragma unroll
        for (int r = 0; r < 4; ++r) {
          const int kvg = kvt * 32 + g * 8 + ft * 4 + r;
          const float v = st[ft][r] * scale;
          ex[ft][r] = (kvg > qrow) ? -1e30f : v;
          mt = fmaxf(mt, ex[ft][r]);
        }
      }
      mt = fmaxf(mt, __shfl_xor(mt, 16));
      mt = fmaxf(mt, __shfl_xor(mt, 32));
      const float mprev = mrun;
      const float mnew = fmaxf(mprev, mt);
      mrun = mnew;
      float psum = 0.0f;
#pragma unroll
      for (int ft = 0; ft < 2; ++ft) {
#pragma unroll
        for (int r = 0; r < 4; ++r) {
          ex[ft][r] = __expf(ex[ft][r] - mnew);
          psum += ex[ft][r];
        }
      }
      psum += __shfl_xor(psum, 16);
      psum += __shfl_xor(psum, 32);

      if (!__all(mt <= mprev)) {  // some q-row's max grew -> rescale O
        const float corr = __expf(mprev - mnew);
        lrun = lrun * corr + psum;
        float cr[4];
#pragma unroll
        for (int r = 0; r < 4; ++r) cr[r] = __shfl(corr, g * 4 + r);
#pragma unroll
        for (int dt = 0; dt < 32; ++dt) {
          oacc[dt][0] *= cr[0];
          oacc[dt][1] *= cr[1];
          oacc[dt][2] *= cr[2];
          oacc[dt][3] *= cr[3];
        }
      } else {
        lrun += psum;
      }

      // ---- P A-frag in-register: pa0[ft*4+r] = P[q=c][kv = g*8 + ft*4 + r]
      bf16x8 pa0;
#pragma unroll
      for (int r = 0; r < 4; ++r) {
        pa0[r] = (short)f2bf(ex[0][r]);
        pa0[r + 4] = (short)f2bf(ex[1][r]);
      }

      // ---- PV: 32 ds_read_b128 (one base + imm) + 32 MFMA
      const char* vp = vb + c * 64 + g * 16;
#pragma unroll
      for (int dt = 0; dt < 32; ++dt) {
        const bf16x8 b0 = *(const bf16x8*)(vp + dt * 1024);
        oacc[dt] = MFMA(pa0, b0, oacc[dt]);
      }
    }

    // ---- epilogue: x + O/l  (oacc[dt][r] = O[q=g*4+r][d=dt*16+c])
    const float rl = 1.0f / lrun;
    float rlr[4];
#pragma unroll
    for (int r = 0; r < 4; ++r) rlr[r] = __shfl(rl, g * 4 + r);
#pragma unroll
    for (int dt = 0; dt < 32; ++dt) {
#pragma unroll
      for (int r = 0; r < 4; ++r) {
        const size_t off =
            bcbase + (size_t)(qt * 128 + wid * 16 + g * 4 + r) * DDIM + dt * 16 + c;
        xo[off] = x[off] + oacc[dt][r] * rlr[r];
      }
    }
    __syncthreads();  // all LDS reads of half h done before half h+1 staging
  }
}

// ---------------- cell mixing + sin pulse (in-place on d_out) ----------------
__global__ __launch_bounds__(256) void k_mix(float* __restrict__ xo,
                                             const float* __restrict__ inh,
                                             const float* __restrict__ phz,
                                             const float* __restrict__ rsc) {
  __shared__ float sI[256];
  __shared__ float sP[16];
  const int tid = threadIdx.x;
  sI[tid] = inh[tid];
  if (tid < 16) sP[tid] = phz[tid];
  __syncthreads();
  const float rs = rsc[0];
  const int idx = blockIdx.x * 256 + tid;
  const int d4 = idx & 127;
  const int t = (idx >> 7) & 1023;
  const int b = idx >> 17;
  float4* base = (float4*)xo + ((size_t)b * 16 * TSEQ + t) * 128 + d4;
  float4 v[16];
#pragma unroll
  for (int cc = 0; cc < 16; ++cc) v[cc] = base[(size_t)cc * TSEQ * 128];
#pragma unroll
  for (int k = 0; k < 16; ++k) {
    float4 comp = make_float4(0.f, 0.f, 0.f, 0.f);
#pragma unroll
    for (int cc = 0; cc < 16; ++cc) {
      const float w = sI[cc * 16 + k];
      comp.x += v[cc].x * w;
      comp.y += v[cc].y * w;
      comp.z += v[cc].z * w;
      comp.w += v[cc].w * w;
    }
    const float ph = sP[k];
    float4 o;
    o.x = v[k].x + __sinf(comp.x + ph) * rs;
    o.y = v[k].y + __sinf(comp.y + ph) * rs;
    o.z = v[k].z + __sinf(comp.z + ph) * rs;
    o.w = v[k].w + __sinf(comp.w + ph) * rs;
    base[(size_t)k * TSEQ * 128] = o;
  }
}

extern "C" void kernel_launch(void* const* d_in, const int* in_sizes, int n_in,
                              void* d_out, int out_size, void* d_ws, size_t ws_size,
                              hipStream_t stream) {
  const float* x = (const float*)d_in[0];
  // d_in[1] = causal mask -- implemented analytically
  const float* gamma = (const float*)d_in[2];
  const float* beta = (const float*)d_in[3];
  const float* Wg = (const float*)d_in[4];
  const float* inh = (const float*)d_in[5];
  const float* phz = (const float*)d_in[6];
  const float* rsc = (const float*)d_in[7];
  float* out = (float*)d_out;

  // ws (>=128MiB, confirmed): qkv (64MiB) + qkvT (64MiB).
  // nx -> d_out[0:64MiB); wgb -> d_out @100MiB (dead before k_attn writes).
  unsigned short* qkv = (unsigned short*)d_ws;
  unsigned short* qkvT = qkv + (size_t)33554432;
  unsigned short* nx = (unsigned short*)d_out;
  unsigned short* wgb = (unsigned short*)((char*)d_out + 104857600);

  k_cast<<<128, 256, 0, stream>>>(Wg, wgb, 32768);
  k_ln<<<16384, 256, 0, stream>>>(x, gamma, beta, nx);
  k_gemm<<<dim3(4, 512), 256, 0, stream>>>(nx, wgb, qkv);
  k_vt<<<dim3(16, 8, 64), 256, 0, stream>>>(qkv, qkvT);
  k_attn<<<dim3(64, 4), 512, 0, stream>>>(qkv, qkvT, x, out);
  k_mix<<<2048, 256, 0, stream>>>(out, inh, phz, rsc);
}